// Round 7
// baseline (1034.877 us; speedup 1.0000x reference)
//
#include <hip/hip_runtime.h>

namespace {
constexpr int D       = 128;
constexpr int K       = 1024;
constexpr int M_TOTAL = 65536;   // 16 * 4096
}

// ---------------- prep: Cn[k] = numpy-pairwise fp32 sum of cb[k,d]^2 ----------------
__global__ void vq_prep(const float* __restrict__ cb, float* __restrict__ Cn) {
  int k = blockIdx.x * 256 + threadIdx.x;
  if (k >= K) return;
  const float* c = cb + (size_t)k * D;
  float r8[8];
#pragma unroll
  for (int j = 0; j < 8; ++j) r8[j] = __fmul_rn(c[j], c[j]);
  for (int i = 8; i < D; i += 8) {
#pragma unroll
    for (int j = 0; j < 8; ++j)
      r8[j] = __fadd_rn(r8[j], __fmul_rn(c[i + j], c[i + j]));
  }
  Cn[k] = __fadd_rn(__fadd_rn(__fadd_rn(r8[0], r8[1]), __fadd_rn(r8[2], r8[3])),
                    __fadd_rn(__fadd_rn(r8[4], r8[5]), __fadd_rn(r8[6], r8[7])));
}

// ---------------- main: row-in-registers, scalar-operand code stream, no LDS ----------------
// One thread = one row. dist[k] = fl( fl( A - fl(2*B_k) ) + C_k );
//   B_k = single sequential fp32 FMA chain over d = 0..127 (bit-exact: validated R4/R5),
//   A   = numpy-pairwise 8-accumulator row norm,
//   argmin: ascending k, strict < -> np.argmin first-occurrence ties.
// Code loads are wave-uniform -> scalar loads (SGPR); z row stays in 32 float4 VGPRs.
__global__ __launch_bounds__(256, 1) void vq_main(
    const float* __restrict__ z, const float* __restrict__ cb,
    const float* __restrict__ Cn,
    float* __restrict__ out_zq, float* __restrict__ out_q,
    float* __restrict__ out_c, float* __restrict__ out_i) {
  const int row = blockIdx.x * 256 + threadIdx.x;   // grid covers M exactly

  // z row -> registers (32 x float4, all indices compile-time after unroll)
  float4 zr[32];
  const float4* zp = reinterpret_cast<const float4*>(z + (size_t)row * D);
#pragma unroll
  for (int i = 0; i < 32; ++i) zr[i] = zp[i];

  // A: numpy pairwise 8-acc row norm. d = 4*d4 + e ; j = d & 7 (even d4 -> e, odd -> 4+e)
  float r8[8];
  r8[0] = __fmul_rn(zr[0].x, zr[0].x); r8[1] = __fmul_rn(zr[0].y, zr[0].y);
  r8[2] = __fmul_rn(zr[0].z, zr[0].z); r8[3] = __fmul_rn(zr[0].w, zr[0].w);
  r8[4] = __fmul_rn(zr[1].x, zr[1].x); r8[5] = __fmul_rn(zr[1].y, zr[1].y);
  r8[6] = __fmul_rn(zr[1].z, zr[1].z); r8[7] = __fmul_rn(zr[1].w, zr[1].w);
#pragma unroll
  for (int d4 = 2; d4 < 32; d4 += 2) {
    r8[0] = __fadd_rn(r8[0], __fmul_rn(zr[d4].x, zr[d4].x));
    r8[1] = __fadd_rn(r8[1], __fmul_rn(zr[d4].y, zr[d4].y));
    r8[2] = __fadd_rn(r8[2], __fmul_rn(zr[d4].z, zr[d4].z));
    r8[3] = __fadd_rn(r8[3], __fmul_rn(zr[d4].w, zr[d4].w));
    r8[4] = __fadd_rn(r8[4], __fmul_rn(zr[d4 + 1].x, zr[d4 + 1].x));
    r8[5] = __fadd_rn(r8[5], __fmul_rn(zr[d4 + 1].y, zr[d4 + 1].y));
    r8[6] = __fadd_rn(r8[6], __fmul_rn(zr[d4 + 1].z, zr[d4 + 1].z));
    r8[7] = __fadd_rn(r8[7], __fmul_rn(zr[d4 + 1].w, zr[d4 + 1].w));
  }
  const float A =
      __fadd_rn(__fadd_rn(__fadd_rn(r8[0], r8[1]), __fadd_rn(r8[2], r8[3])),
                __fadd_rn(__fadd_rn(r8[4], r8[5]), __fadd_rn(r8[6], r8[7])));

  // scan all codes; per-lane argmin
  float best = 3.402823466e+38f;
  int   bi   = 0;
  const float4* cv4 = reinterpret_cast<const float4*>(cb);
#pragma unroll 2
  for (int k = 0; k < K; ++k) {
    float acc = 0.f;   // sequential fp32 FMA chain, d ascending (bit-exact order)
#pragma unroll
    for (int d4 = 0; d4 < 32; ++d4) {
      float4 c4 = cv4[k * 32 + d4];   // wave-uniform address -> scalar load
      acc = fmaf(c4.x, zr[d4].x, acc);
      acc = fmaf(c4.y, zr[d4].y, acc);
      acc = fmaf(c4.z, zr[d4].z, acc);
      acc = fmaf(c4.w, zr[d4].w, acc);
    }
    float dist = __fadd_rn(__fsub_rn(A, __fmul_rn(2.0f, acc)), Cn[k]);
    if (dist < best) { best = dist; bi = k; }   // strict <: first index wins
  }

  // epilogue: gather chosen code, STE, losses, index (all from registers)
  const float4* cq = reinterpret_cast<const float4*>(cb + (size_t)bi * D);
  float4* o4 = reinterpret_cast<float4*>(out_zq + (size_t)row * D);
  float sum = 0.f;
#pragma unroll
  for (int d4 = 0; d4 < 32; ++d4) {
    float4 cv = cq[d4];
    float dx = cv.x - zr[d4].x, dy = cv.y - zr[d4].y;
    float dz = cv.z - zr[d4].z, dw = cv.w - zr[d4].w;
    float4 st;
    st.x = zr[d4].x + dx; st.y = zr[d4].y + dy;
    st.z = zr[d4].z + dz; st.w = zr[d4].w + dw;
    o4[d4] = st;
    sum = fmaf(dx, dx, sum); sum = fmaf(dy, dy, sum);
    sum = fmaf(dz, dz, sum); sum = fmaf(dw, dw, sum);
  }
  float lv = sum * 0.0078125f;   // /128
  out_q[row] = lv;
  out_c[row] = lv;
  out_i[row] = (float)bi;
}

extern "C" void kernel_launch(void* const* d_in, const int* in_sizes, int n_in,
                              void* d_out, int out_size, void* d_ws, size_t ws_size,
                              hipStream_t stream) {
  const float* z  = (const float*)d_in[0];   // [16,4096,128] fp32
  const float* cb = (const float*)d_in[1];   // [1024,128] fp32

  float* out0 = (float*)d_out;               // z_q_ste  [M,128]
  float* out1 = out0 + (size_t)M_TOTAL * D;  // quant_loss [M]
  float* out2 = out1 + M_TOTAL;              // commit_loss [M]
  float* out3 = out2 + M_TOTAL;              // indices (as float) [M]

  float* Cn = (float*)d_ws;                  // numpy-pairwise |c_k|^2 [1024] (4 KB)

  vq_prep<<<(K + 255) / 256, 256, 0, stream>>>(cb, Cn);
  vq_main<<<M_TOTAL / 256, 256, 0, stream>>>(z, cb, Cn, out0, out1, out2, out3);
}

// Round 8
// 476.174 us; speedup vs baseline: 2.1733x; 2.1733x over previous
//
#include <hip/hip_runtime.h>

namespace {
constexpr int D       = 128;
constexpr int K       = 1024;
constexpr int M_TOTAL = 65536;   // 16 * 4096
constexpr int BM      = 128;     // rows per block
constexpr int BKT     = 128;     // codes per kt tile
constexpr int NKT     = K / BKT; // 8
constexpr float TAU   = 1.0e-4f; // candidate margin: quant span ~6e-5 + scoring err + slack
}

typedef short bf16x8 __attribute__((ext_vector_type(8)));
typedef float f32x4  __attribute__((ext_vector_type(4)));

static __device__ __forceinline__ unsigned short f2bf(float x) {
  unsigned u = __float_as_uint(x);
  return (unsigned short)((u + 0x7FFFu + ((u >> 16) & 1u)) >> 16);  // RNE
}
static __device__ __forceinline__ float bf2f(unsigned short h) {
  return __uint_as_float(((unsigned)h) << 16);
}

// ---------------- prep: Cn[k] = numpy-pairwise fp32 sum of cb[k,d]^2 ----------------
__global__ void vq_prep(const float* __restrict__ cb, float* __restrict__ Cn) {
  int k = blockIdx.x * 256 + threadIdx.x;
  if (k >= K) return;
  const float* c = cb + (size_t)k * D;
  float r8[8];
#pragma unroll
  for (int j = 0; j < 8; ++j) r8[j] = __fmul_rn(c[j], c[j]);
  for (int i = 8; i < D; i += 8) {
#pragma unroll
    for (int j = 0; j < 8; ++j)
      r8[j] = __fadd_rn(r8[j], __fmul_rn(c[i + j], c[i + j]));
  }
  Cn[k] = __fadd_rn(__fadd_rn(__fadd_rn(r8[0], r8[1]), __fadd_rn(r8[2], r8[3])),
                    __fadd_rn(__fadd_rn(r8[4], r8[5]), __fadd_rn(r8[6], r8[7])));
}

// ---------------- main: bf16-split MFMA scoring + margin + exact-fp32 fallback ----------------
// Fragment LDS layout per plane: [tile(8)][kstep(4)][lane(64)][8 bf16]
//   A: lane = (row&15) + 16*kgrp, elems k = kgrp*8..+7  (row-tile = row>>4)
//   B: lane = (col&15) + 16*kgrp                        (col-tile = code>>4)
// frag offset (halfwords):
#define FRAG(tile, ks, lane) ((((tile) * 4 + (ks)) * 64 + (lane)) * 8)

__global__ __launch_bounds__(256, 1) void vq_main(
    const float* __restrict__ z, const float* __restrict__ cb,
    const float* __restrict__ Cn,
    float* __restrict__ out_zq, float* __restrict__ out_q,
    float* __restrict__ out_c, float* __restrict__ out_i) {
  __shared__ short Ah[8 * 4 * 64 * 8];   // 32 KB  z hi
  __shared__ short Al[8 * 4 * 64 * 8];   // 32 KB  z lo
  __shared__ short Bh[8 * 4 * 64 * 8];   // 32 KB  code hi (per kt)
  __shared__ short Bl[8 * 4 * 64 * 8];   // 32 KB  code lo (per kt)
  __shared__ float sRed[256];
  __shared__ int   iRed[256];
  __shared__ int   idxArr[BM];
  __shared__ int   hardRows[BM];
  __shared__ int   hardCnt;

  const int t    = threadIdx.x;
  const int wave = t >> 6;
  const int lane = t & 63;
  const int baseRow = blockIdx.x * BM;

  if (t == 0) hardCnt = 0;

  // ---- stage Z tile -> hi/lo fragment planes (once) ----
  const float4* z4  = reinterpret_cast<const float4*>(z);
  const float4* cb4 = reinterpret_cast<const float4*>(cb);
  for (int s = t; s < BM * 32; s += 256) {
    int r = s >> 5, d4 = s & 31;
    float4 v = z4[(size_t)(baseRow + r) * 32 + d4];
    int q = d4 & 7, ks = d4 >> 3;
    int ln = (r & 15) + 16 * (q >> 1);
    int off = FRAG(r >> 4, ks, ln) + (q & 1) * 4;
    unsigned short hx = f2bf(v.x), hy = f2bf(v.y), hz = f2bf(v.z), hw = f2bf(v.w);
    unsigned short lx = f2bf(v.x - bf2f(hx)), ly = f2bf(v.y - bf2f(hy));
    unsigned short lz = f2bf(v.z - bf2f(hz)), lw = f2bf(v.w - bf2f(hw));
    *reinterpret_cast<uint2*>(&Ah[off]) =
        make_uint2((unsigned)hx | ((unsigned)hy << 16), (unsigned)hz | ((unsigned)hw << 16));
    *reinterpret_cast<uint2*>(&Al[off]) =
        make_uint2((unsigned)lx | ((unsigned)ly << 16), (unsigned)lz | ((unsigned)lw << 16));
  }

  // per-lane trackers: 8 row-slots (2 rowtiles x 4 regs)
  float s1[8], s2[8]; int i1[8];
#pragma unroll
  for (int i = 0; i < 8; ++i) { s1[i] = 3.402823466e+38f; s2[i] = 3.402823466e+38f; i1[i] = 0; }

  for (int kt = 0; kt < NKT; ++kt) {
    __syncthreads();   // previous compute done (and A staging visible on kt==0)
    // ---- stage code tile -> hi/lo fragment planes ----
    for (int s = t; s < BKT * 32; s += 256) {
      int c = s >> 5, d4 = s & 31;
      float4 v = cb4[(size_t)(kt * BKT + c) * 32 + d4];
      int q = d4 & 7, ks = d4 >> 3;
      int ln = (c & 15) + 16 * (q >> 1);
      int off = FRAG(c >> 4, ks, ln) + (q & 1) * 4;
      unsigned short hx = f2bf(v.x), hy = f2bf(v.y), hz = f2bf(v.z), hw = f2bf(v.w);
      unsigned short lx = f2bf(v.x - bf2f(hx)), ly = f2bf(v.y - bf2f(hy));
      unsigned short lz = f2bf(v.z - bf2f(hz)), lw = f2bf(v.w - bf2f(hw));
      *reinterpret_cast<uint2*>(&Bh[off]) =
          make_uint2((unsigned)hx | ((unsigned)hy << 16), (unsigned)hz | ((unsigned)hw << 16));
      *reinterpret_cast<uint2*>(&Bl[off]) =
          make_uint2((unsigned)lx | ((unsigned)ly << 16), (unsigned)lz | ((unsigned)lw << 16));
    }
    __syncthreads();

    // ---- MFMA: 32 rows x 128 codes per wave; 3-term bf16 split ----
    f32x4 acc[2][8];
#pragma unroll
    for (int a = 0; a < 2; ++a)
#pragma unroll
      for (int b = 0; b < 8; ++b) acc[a][b] = (f32x4){0.f, 0.f, 0.f, 0.f};

#pragma unroll
    for (int ks = 0; ks < 4; ++ks) {
      bf16x8 ah[2], al[2];
#pragma unroll
      for (int rtl = 0; rtl < 2; ++rtl) {
        ah[rtl] = *reinterpret_cast<const bf16x8*>(&Ah[FRAG(wave * 2 + rtl, ks, lane)]);
        al[rtl] = *reinterpret_cast<const bf16x8*>(&Al[FRAG(wave * 2 + rtl, ks, lane)]);
      }
#pragma unroll
      for (int h = 0; h < 2; ++h) {
        bf16x8 bh[4], bl[4];
#pragma unroll
        for (int c4 = 0; c4 < 4; ++c4) {
          int ct = h * 4 + c4;
          bh[c4] = *reinterpret_cast<const bf16x8*>(&Bh[FRAG(ct, ks, lane)]);
          bl[c4] = *reinterpret_cast<const bf16x8*>(&Bl[FRAG(ct, ks, lane)]);
        }
#pragma unroll
        for (int rtl = 0; rtl < 2; ++rtl)
#pragma unroll
          for (int c4 = 0; c4 < 4; ++c4) {
            int ct = h * 4 + c4;
            acc[rtl][ct] = __builtin_amdgcn_mfma_f32_16x16x32_bf16(ah[rtl], bh[c4], acc[rtl][ct], 0, 0, 0);
            acc[rtl][ct] = __builtin_amdgcn_mfma_f32_16x16x32_bf16(ah[rtl], bl[c4], acc[rtl][ct], 0, 0, 0);
            acc[rtl][ct] = __builtin_amdgcn_mfma_f32_16x16x32_bf16(al[rtl], bh[c4], acc[rtl][ct], 0, 0, 0);
          }
      }
    }

    // ---- tracker update: S = Cn - 2B (approx ok; margin covers) ----
    const int col = lane & 15;
#pragma unroll
    for (int ct = 0; ct < 8; ++ct) {
      int code = kt * BKT + ct * 16 + col;
      float cn = Cn[code];
#pragma unroll
      for (int rtl = 0; rtl < 2; ++rtl)
#pragma unroll
        for (int reg = 0; reg < 4; ++reg) {
          float S = fmaf(-2.0f, acc[rtl][ct][reg], cn);
          int slot = rtl * 4 + reg;
          if (S < s1[slot]) { s2[slot] = s1[slot]; s1[slot] = S; i1[slot] = code; }
          else if (S < s2[slot]) { s2[slot] = S; }
        }
    }
  }

  // ---- cross-lane (16-lane group) min1/min2 merge ----
#pragma unroll
  for (int m = 1; m < 16; m <<= 1) {
#pragma unroll
    for (int slot = 0; slot < 8; ++slot) {
      float os1 = __shfl_xor(s1[slot], m, 64);
      float os2 = __shfl_xor(s2[slot], m, 64);
      int   oi  = __shfl_xor(i1[slot], m, 64);
      if (os1 < s1[slot]) { s2[slot] = fminf(s1[slot], os2); s1[slot] = os1; i1[slot] = oi; }
      else                { s2[slot] = fminf(s2[slot], os1); }
    }
  }

  if ((lane & 15) == 0) {
#pragma unroll
    for (int slot = 0; slot < 8; ++slot) {
      int row = (wave * 2 + (slot >> 2)) * 16 + (lane >> 4) * 4 + (slot & 3);
      idxArr[row] = i1[slot];
      if (s2[slot] - s1[slot] < TAU) {
        int p = atomicAdd(&hardCnt, 1);
        hardRows[p] = row;
      }
    }
  }
  __syncthreads();

  // ---- hard rows: bit-exact numpy-fp32 full-K rescan (validated R4 recipe) ----
  const int nh = hardCnt;
  for (int f = 0; f < nh; ++f) {
    const int row = hardRows[f];
    const float*  zp  = z + (size_t)(baseRow + row) * D;
    const float4* zp4 = reinterpret_cast<const float4*>(zp);
    // numpy pairwise-8 A (uniform, redundant per thread)
    float r8[8];
#pragma unroll
    for (int j = 0; j < 8; ++j) r8[j] = __fmul_rn(zp[j], zp[j]);
    for (int i = 8; i < D; i += 8) {
#pragma unroll
      for (int j = 0; j < 8; ++j)
        r8[j] = __fadd_rn(r8[j], __fmul_rn(zp[i + j], zp[i + j]));
    }
    float A = __fadd_rn(__fadd_rn(__fadd_rn(r8[0], r8[1]), __fadd_rn(r8[2], r8[3])),
                        __fadd_rn(__fadd_rn(r8[4], r8[5]), __fadd_rn(r8[6], r8[7])));
    // 4 codes per thread, sequential fp32 FMA chains (ascending d)
    const int kb = t * 4;
    float acc4[4] = {0.f, 0.f, 0.f, 0.f};
    const float4* cp0 = reinterpret_cast<const float4*>(cb + (size_t)(kb + 0) * D);
    const float4* cp1 = reinterpret_cast<const float4*>(cb + (size_t)(kb + 1) * D);
    const float4* cp2 = reinterpret_cast<const float4*>(cb + (size_t)(kb + 2) * D);
    const float4* cp3 = reinterpret_cast<const float4*>(cb + (size_t)(kb + 3) * D);
#pragma unroll 8
    for (int d4 = 0; d4 < 32; ++d4) {
      float4 zv = zp4[d4];
      float4 c0 = cp0[d4], c1 = cp1[d4], c2 = cp2[d4], c3 = cp3[d4];
      acc4[0] = fmaf(zv.x, c0.x, acc4[0]); acc4[0] = fmaf(zv.y, c0.y, acc4[0]);
      acc4[0] = fmaf(zv.z, c0.z, acc4[0]); acc4[0] = fmaf(zv.w, c0.w, acc4[0]);
      acc4[1] = fmaf(zv.x, c1.x, acc4[1]); acc4[1] = fmaf(zv.y, c1.y, acc4[1]);
      acc4[1] = fmaf(zv.z, c1.z, acc4[1]); acc4[1] = fmaf(zv.w, c1.w, acc4[1]);
      acc4[2] = fmaf(zv.x, c2.x, acc4[2]); acc4[2] = fmaf(zv.y, c2.y, acc4[2]);
      acc4[2] = fmaf(zv.z, c2.z, acc4[2]); acc4[2] = fmaf(zv.w, c2.w, acc4[2]);
      acc4[3] = fmaf(zv.x, c3.x, acc4[3]); acc4[3] = fmaf(zv.y, c3.y, acc4[3]);
      acc4[3] = fmaf(zv.z, c3.z, acc4[3]); acc4[3] = fmaf(zv.w, c3.w, acc4[3]);
    }
    float bd = 3.402823466e+38f; int bi = 0;
#pragma unroll
    for (int c = 0; c < 4; ++c) {   // ascending k; strict < keeps first index
      float dist = __fadd_rn(__fsub_rn(A, __fmul_rn(2.0f, acc4[c])), Cn[kb + c]);
      if (dist < bd) { bd = dist; bi = kb + c; }
    }
    sRed[t] = bd; iRed[t] = bi;
    __syncthreads();
    for (int w = 128; w > 0; w >>= 1) {
      if (t < w) {
        float o = sRed[t + w]; int oi = iRed[t + w];
        if (o < sRed[t] || (o == sRed[t] && oi < iRed[t])) { sRed[t] = o; iRed[t] = oi; }
      }
      __syncthreads();
    }
    if (t == 0) idxArr[row] = iRed[0];
    __syncthreads();
  }

  // ---- epilogue: gather z_q, STE, losses, index (2 threads per row) ----
  {
    int r = t >> 1, q = t & 1;
    int idx = idxArr[r];
    size_t m = (size_t)baseRow + r;
    const float4* cq  = reinterpret_cast<const float4*>(cb + (size_t)idx * D) + q * 16;
    const float4* zr4 = reinterpret_cast<const float4*>(z + m * D) + q * 16;
    float4*       o4  = reinterpret_cast<float4*>(out_zq + m * D) + q * 16;
    float sum = 0.f;
#pragma unroll
    for (int e = 0; e < 16; ++e) {
      float4 cv = cq[e];
      float4 zv = zr4[e];
      float dx = cv.x - zv.x, dy = cv.y - zv.y, dz = cv.z - zv.z, dw = cv.w - zv.w;
      float4 st;
      st.x = zv.x + dx; st.y = zv.y + dy; st.z = zv.z + dz; st.w = zv.w + dw;
      o4[e] = st;
      sum = fmaf(dx, dx, sum); sum = fmaf(dy, dy, sum);
      sum = fmaf(dz, dz, sum); sum = fmaf(dw, dw, sum);
    }
    sum += __shfl_xor(sum, 1, 64);
    if (q == 0) {
      float lv = sum * 0.0078125f;   // /128
      out_q[m] = lv;
      out_c[m] = lv;
      out_i[m] = (float)idx;
    }
  }
}

extern "C" void kernel_launch(void* const* d_in, const int* in_sizes, int n_in,
                              void* d_out, int out_size, void* d_ws, size_t ws_size,
                              hipStream_t stream) {
  const float* z  = (const float*)d_in[0];   // [16,4096,128] fp32
  const float* cb = (const float*)d_in[1];   // [1024,128] fp32

  float* out0 = (float*)d_out;               // z_q_ste  [M,128]
  float* out1 = out0 + (size_t)M_TOTAL * D;  // quant_loss [M]
  float* out2 = out1 + M_TOTAL;              // commit_loss [M]
  float* out3 = out2 + M_TOTAL;              // indices (as float) [M]

  float* Cn = (float*)d_ws;                  // numpy-pairwise |c_k|^2 [1024] (4 KB)

  vq_prep<<<(K + 255) / 256, 256, 0, stream>>>(cb, Cn);
  vq_main<<<M_TOTAL / BM, 256, 0, stream>>>(z, cb, Cn, out0, out1, out2, out3);
}

// Round 9
// 321.490 us; speedup vs baseline: 3.2190x; 1.4811x over previous
//
#include <hip/hip_runtime.h>
#include <hip/hip_bf16.h>

namespace {
constexpr int D       = 128;
constexpr int K       = 1024;
constexpr int M_TOTAL = 65536;   // 16 * 4096
constexpr int BM      = 64;      // rows per block
constexpr int BKT     = 64;      // codes per kt tile
constexpr int NKT     = K / BKT; // 16
constexpr float TAU   = 1.0e-4f; // provably covers numpy quantization span + scorer err
}

typedef short bf16x8 __attribute__((ext_vector_type(8)));
typedef float f32x4  __attribute__((ext_vector_type(4)));

static __device__ __forceinline__ unsigned short bfbits(float x) {
  __hip_bfloat16 h = __float2bfloat16(x);           // RNE; compiler may fuse to cvt_pk
  return *reinterpret_cast<unsigned short*>(&h);
}
static __device__ __forceinline__ float bfhi2f(unsigned short h) {
  return __uint_as_float(((unsigned)h) << 16);
}

// ---------------- prep: Cn[k] = numpy-pairwise fp32 sum of cb[k,d]^2 ----------------
__global__ void vq_prep(const float* __restrict__ cb, float* __restrict__ Cn) {
  int k = blockIdx.x * 256 + threadIdx.x;
  if (k >= K) return;
  const float* c = cb + (size_t)k * D;
  float r8[8];
#pragma unroll
  for (int j = 0; j < 8; ++j) r8[j] = __fmul_rn(c[j], c[j]);
  for (int i = 8; i < D; i += 8) {
#pragma unroll
    for (int j = 0; j < 8; ++j)
      r8[j] = __fadd_rn(r8[j], __fmul_rn(c[i + j], c[i + j]));
  }
  Cn[k] = __fadd_rn(__fadd_rn(__fadd_rn(r8[0], r8[1]), __fadd_rn(r8[2], r8[3])),
                    __fadd_rn(__fadd_rn(r8[4], r8[5]), __fadd_rn(r8[6], r8[7])));
}

// Fragment LDS layout per plane: [tile(4)][ks(4)][lane(64)][8 bf16]  (R8-validated)
//   lane ln holds row/col = tile*16 + (ln&15), d = ks*32 + (ln>>4)*8 + el
#define FRAG(tile, ks, lane) ((((tile) * 4 + (ks)) * 64 + (lane)) * 8)

// plane-linear staging: thread owns uint2 slot u; decode (tile,ks,ln,el4) from u
#define U_DECODE(u, tile, ks, ln, el4)  \
  int el4 = ((u) & 1) * 4;              \
  int ln  = ((u) >> 1) & 63;            \
  int ks  = ((u) >> 7) & 3;             \
  int tile = (u) >> 9;

static __device__ __forceinline__ void cvt_write(short* __restrict__ Ph,
                                                 short* __restrict__ Pl,
                                                 int u, float4 v) {
  unsigned short hx = bfbits(v.x), hy = bfbits(v.y), hz = bfbits(v.z), hw = bfbits(v.w);
  float rx = v.x - bfhi2f(hx), ry = v.y - bfhi2f(hy);
  float rz = v.z - bfhi2f(hz), rw = v.w - bfhi2f(hw);
  unsigned short lx = bfbits(rx), ly = bfbits(ry), lz = bfbits(rz), lw = bfbits(rw);
  *reinterpret_cast<uint2*>(&Ph[u * 4]) =
      make_uint2((unsigned)hx | ((unsigned)hy << 16), (unsigned)hz | ((unsigned)hw << 16));
  *reinterpret_cast<uint2*>(&Pl[u * 4]) =
      make_uint2((unsigned)lx | ((unsigned)ly << 16), (unsigned)lz | ((unsigned)lw << 16));
}

// ---------------- main: bf16-split MFMA + margin + exact numpy-fp32 fallback ----------------
__global__ __launch_bounds__(256, 2) void vq_main(
    const float* __restrict__ z, const float* __restrict__ cb,
    const float* __restrict__ Cn,
    float* __restrict__ out_zq, float* __restrict__ out_q,
    float* __restrict__ out_c, float* __restrict__ out_i) {
  __shared__ short Ah[4 * 4 * 64 * 8];   // 16 KB  z hi   (persistent)
  __shared__ short Al[4 * 4 * 64 * 8];   // 16 KB  z lo
  __shared__ short Bh[4 * 4 * 64 * 8];   // 16 KB  code hi (per kt)
  __shared__ short Bl[4 * 4 * 64 * 8];   // 16 KB  code lo
  __shared__ float sRed[256];
  __shared__ int   iRed[256];
  __shared__ int   idxArr[BM];
  __shared__ int   hardRows[BM];
  __shared__ int   hardCnt;

  const int t    = threadIdx.x;
  const int wave = t >> 6;
  const int lane = t & 63;
  const int baseRow = blockIdx.x * BM;

  if (t == 0) hardCnt = 0;

  const float4* z4  = reinterpret_cast<const float4*>(z);
  const float4* cb4 = reinterpret_cast<const float4*>(cb);

  // ---- stage Z planes once (plane-linear thread assignment: conflict-free writes) ----
  for (int u = t; u < 2048; u += 256) {
    U_DECODE(u, tile, ks, ln, el4);
    int row = tile * 16 + (ln & 15);
    int db  = ks * 32 + (ln >> 4) * 8 + el4;
    float4 v = z4[(size_t)(baseRow + row) * 32 + (db >> 2)];
    cvt_write(Ah, Al, u, v);
  }

  // ---- prefetch B tile 0 into registers ----
  float4 pf[8];
#pragma unroll
  for (int i = 0; i < 8; ++i) {
    int u = t + i * 256;
    U_DECODE(u, tile, ks, ln, el4);
    int code = tile * 16 + (ln & 15);
    int db   = ks * 32 + (ln >> 4) * 8 + el4;
    pf[i] = cb4[(size_t)code * 32 + (db >> 2)];
  }

  float s1[4], s2[4]; int i1[4];
#pragma unroll
  for (int i = 0; i < 4; ++i) { s1[i] = 3.402823466e+38f; s2[i] = 3.402823466e+38f; i1[i] = 0; }

  for (int kt = 0; kt < NKT; ++kt) {
    // write prefetched tile into planes (prev compute finished at loop-end barrier)
#pragma unroll
    for (int i = 0; i < 8; ++i) cvt_write(Bh, Bl, t + i * 256, pf[i]);
    __syncthreads();

    // T14: issue next tile's global loads now; they complete during compute
    if (kt + 1 < NKT) {
#pragma unroll
      for (int i = 0; i < 8; ++i) {
        int u = t + i * 256;
        U_DECODE(u, tile, ks, ln, el4);
        int code = (kt + 1) * BKT + tile * 16 + (ln & 15);
        int db   = ks * 32 + (ln >> 4) * 8 + el4;
        pf[i] = cb4[(size_t)code * 32 + (db >> 2)];
      }
    }

    // ---- MFMA: 16 rows (tile=wave) x 64 codes; 3-term bf16 split ----
    f32x4 acc[4];
#pragma unroll
    for (int ct = 0; ct < 4; ++ct) acc[ct] = (f32x4){0.f, 0.f, 0.f, 0.f};

#pragma unroll
    for (int ks = 0; ks < 4; ++ks) {
      bf16x8 ah = *reinterpret_cast<const bf16x8*>(&Ah[FRAG(wave, ks, lane)]);
      bf16x8 al = *reinterpret_cast<const bf16x8*>(&Al[FRAG(wave, ks, lane)]);
#pragma unroll
      for (int ct = 0; ct < 4; ++ct) {
        bf16x8 bh = *reinterpret_cast<const bf16x8*>(&Bh[FRAG(ct, ks, lane)]);
        bf16x8 bl = *reinterpret_cast<const bf16x8*>(&Bl[FRAG(ct, ks, lane)]);
        acc[ct] = __builtin_amdgcn_mfma_f32_16x16x32_bf16(ah, bh, acc[ct], 0, 0, 0);
        acc[ct] = __builtin_amdgcn_mfma_f32_16x16x32_bf16(ah, bl, acc[ct], 0, 0, 0);
        acc[ct] = __builtin_amdgcn_mfma_f32_16x16x32_bf16(al, bh, acc[ct], 0, 0, 0);
      }
    }

    // ---- tracker: S = Cn - 2B ; ascending code order per lane ----
    const int col = lane & 15;
#pragma unroll
    for (int ct = 0; ct < 4; ++ct) {
      int code = kt * BKT + ct * 16 + col;
      float cn = Cn[code];
#pragma unroll
      for (int reg = 0; reg < 4; ++reg) {
        float S = fmaf(-2.0f, acc[ct][reg], cn);
        if (S < s1[reg]) { s2[reg] = s1[reg]; s1[reg] = S; i1[reg] = code; }
        else if (S < s2[reg]) { s2[reg] = S; }
      }
    }
    __syncthreads();   // compute done before next tile overwrite
  }

  // ---- cross-lane (16-col group) min1/min2 merge ----
#pragma unroll
  for (int m = 1; m < 16; m <<= 1) {
#pragma unroll
    for (int reg = 0; reg < 4; ++reg) {
      float os1 = __shfl_xor(s1[reg], m, 64);
      float os2 = __shfl_xor(s2[reg], m, 64);
      int   oi  = __shfl_xor(i1[reg], m, 64);
      if (os1 < s1[reg]) { s2[reg] = fminf(s1[reg], os2); s1[reg] = os1; i1[reg] = oi; }
      else               { s2[reg] = fminf(s2[reg], os1); }
    }
  }

  if ((lane & 15) == 0) {
#pragma unroll
    for (int reg = 0; reg < 4; ++reg) {
      int row = wave * 16 + (lane >> 4) * 4 + reg;
      idxArr[row] = i1[reg];
      if (s2[reg] - s1[reg] < TAU) {
        int p = atomicAdd(&hardCnt, 1);
        hardRows[p] = row;
      }
    }
  }
  __syncthreads();

  // ---- hard rows: bit-exact numpy-fp32 full-K rescan (R4/R8-validated recipe) ----
  const int nh = hardCnt;
  for (int f = 0; f < nh; ++f) {
    const int row = hardRows[f];
    const float*  zp  = z + (size_t)(baseRow + row) * D;
    const float4* zp4 = reinterpret_cast<const float4*>(zp);
    float r8[8];
#pragma unroll
    for (int j = 0; j < 8; ++j) r8[j] = __fmul_rn(zp[j], zp[j]);
    for (int i = 8; i < D; i += 8) {
#pragma unroll
      for (int j = 0; j < 8; ++j)
        r8[j] = __fadd_rn(r8[j], __fmul_rn(zp[i + j], zp[i + j]));
    }
    float A = __fadd_rn(__fadd_rn(__fadd_rn(r8[0], r8[1]), __fadd_rn(r8[2], r8[3])),
                        __fadd_rn(__fadd_rn(r8[4], r8[5]), __fadd_rn(r8[6], r8[7])));
    const int kb = t * 4;
    float acc4[4] = {0.f, 0.f, 0.f, 0.f};
    const float4* cp0 = reinterpret_cast<const float4*>(cb + (size_t)(kb + 0) * D);
    const float4* cp1 = reinterpret_cast<const float4*>(cb + (size_t)(kb + 1) * D);
    const float4* cp2 = reinterpret_cast<const float4*>(cb + (size_t)(kb + 2) * D);
    const float4* cp3 = reinterpret_cast<const float4*>(cb + (size_t)(kb + 3) * D);
#pragma unroll 8
    for (int d4 = 0; d4 < 32; ++d4) {
      float4 zv = zp4[d4];
      float4 c0 = cp0[d4], c1 = cp1[d4], c2 = cp2[d4], c3 = cp3[d4];
      acc4[0] = fmaf(zv.x, c0.x, acc4[0]); acc4[0] = fmaf(zv.y, c0.y, acc4[0]);
      acc4[0] = fmaf(zv.z, c0.z, acc4[0]); acc4[0] = fmaf(zv.w, c0.w, acc4[0]);
      acc4[1] = fmaf(zv.x, c1.x, acc4[1]); acc4[1] = fmaf(zv.y, c1.y, acc4[1]);
      acc4[1] = fmaf(zv.z, c1.z, acc4[1]); acc4[1] = fmaf(zv.w, c1.w, acc4[1]);
      acc4[2] = fmaf(zv.x, c2.x, acc4[2]); acc4[2] = fmaf(zv.y, c2.y, acc4[2]);
      acc4[2] = fmaf(zv.z, c2.z, acc4[2]); acc4[2] = fmaf(zv.w, c2.w, acc4[2]);
      acc4[3] = fmaf(zv.x, c3.x, acc4[3]); acc4[3] = fmaf(zv.y, c3.y, acc4[3]);
      acc4[3] = fmaf(zv.z, c3.z, acc4[3]); acc4[3] = fmaf(zv.w, c3.w, acc4[3]);
    }
    float bd = 3.402823466e+38f; int bi = 0;
#pragma unroll
    for (int c = 0; c < 4; ++c) {   // ascending k; strict < keeps first index
      float dist = __fadd_rn(__fsub_rn(A, __fmul_rn(2.0f, acc4[c])), Cn[kb + c]);
      if (dist < bd) { bd = dist; bi = kb + c; }
    }
    sRed[t] = bd; iRed[t] = bi;
    __syncthreads();
    for (int w = 128; w > 0; w >>= 1) {
      if (t < w) {
        float o = sRed[t + w]; int oi = iRed[t + w];
        if (o < sRed[t] || (o == sRed[t] && oi < iRed[t])) { sRed[t] = o; iRed[t] = oi; }
      }
      __syncthreads();
    }
    if (t == 0) idxArr[row] = iRed[0];
    __syncthreads();
  }

  // ---- epilogue: gather z_q, STE, losses, index (4 threads per row) ----
  {
    int r = t >> 2, q = t & 3;
    int idx = idxArr[r];
    size_t m = (size_t)baseRow + r;
    const float4* cq  = reinterpret_cast<const float4*>(cb + (size_t)idx * D);
    const float4* zr4 = reinterpret_cast<const float4*>(z + m * D);
    float4*       o4  = reinterpret_cast<float4*>(out_zq + m * D);
    float sum = 0.f;
#pragma unroll
    for (int e = 0; e < 8; ++e) {
      int d4 = q * 8 + e;
      float4 cv = cq[d4];
      float4 zv = zr4[d4];
      float dx = cv.x - zv.x, dy = cv.y - zv.y, dz = cv.z - zv.z, dw = cv.w - zv.w;
      float4 st;
      st.x = zv.x + dx; st.y = zv.y + dy; st.z = zv.z + dz; st.w = zv.w + dw;
      o4[d4] = st;
      sum = fmaf(dx, dx, sum); sum = fmaf(dy, dy, sum);
      sum = fmaf(dz, dz, sum); sum = fmaf(dw, dw, sum);
    }
    sum += __shfl_xor(sum, 1, 64);
    sum += __shfl_xor(sum, 2, 64);
    if (q == 0) {
      float lv = sum * 0.0078125f;   // /128
      out_q[m] = lv;
      out_c[m] = lv;
      out_i[m] = (float)idx;
    }
  }
}

extern "C" void kernel_launch(void* const* d_in, const int* in_sizes, int n_in,
                              void* d_out, int out_size, void* d_ws, size_t ws_size,
                              hipStream_t stream) {
  const float* z  = (const float*)d_in[0];   // [16,4096,128] fp32
  const float* cb = (const float*)d_in[1];   // [1024,128] fp32

  float* out0 = (float*)d_out;               // z_q_ste  [M,128]
  float* out1 = out0 + (size_t)M_TOTAL * D;  // quant_loss [M]
  float* out2 = out1 + M_TOTAL;              // commit_loss [M]
  float* out3 = out2 + M_TOTAL;              // indices (as float) [M]

  float* Cn = (float*)d_ws;                  // numpy-pairwise |c_k|^2 [1024] (4 KB)

  vq_prep<<<(K + 255) / 256, 256, 0, stream>>>(cb, Cn);
  vq_main<<<M_TOTAL / BM, 256, 0, stream>>>(z, cb, Cn, out0, out1, out2, out3);
}